// Round 1
// baseline (82.388 us; speedup 1.0000x reference)
//
#include <hip/hip_runtime.h>

// CTC loss forward (T=512, B=1024, C=63, S=25, L=51).
// One wave64 per batch element: lane s owns extended state s.
// Depth-7 register prefetch ring hides HBM latency (1 wave/SIMD, no TLP).

#define TT 512
#define BB 1024
#define CC 63
#define SS 25
#define PF 7              // 511 steps = 73 * 7 -> uniform ring, fully unrolled
#define NEGV (-1e30f)

__global__ __launch_bounds__(256) void ctc_alpha_kernel(
    const float* __restrict__ logp,
    const int* __restrict__ targets,
    const int* __restrict__ tlen,
    float* __restrict__ loss) {
  const int lane = threadIdx.x & 63;
  const int b = (blockIdx.x << 2) + (threadIdx.x >> 6);  // 4 waves/block
  const int* tg = targets + b * SS;
  const int len = tlen[b];

  // ext[s]: even s -> blank(0); odd s -> targets[b, (s-1)/2]
  int e = 0;
  bool skip = false;
  if (lane & 1) {
    const int i = lane >> 1;          // (s-1)/2 for odd s
    if (i < SS) {
      e = tg[i];
      skip = (e != 0) && (i == 0 || e != tg[i - 1]);  // ext != prev2 rule
    }
  }

  const size_t stride = (size_t)BB * CC;          // floats between timesteps
  const float* p = logp + (size_t)b * CC + e;     // this lane's class column

  // t=0 init: only states 0 (blank) and 1 (first label) reachable
  float alpha = (lane <= 1) ? p[0] : NEGV;

  // prefetch ring: pf[j] holds lp(t = tb + j)
  float pf[PF];
#pragma unroll
  for (int j = 0; j < PF; ++j) pf[j] = p[(size_t)(j + 1) * stride];

  for (int tb = 1; tb < TT; tb += PF) {
#pragma unroll
    for (int j = 0; j < PF; ++j) {
      const int t = tb + j;
      const float cur = pf[j];
      int tn = t + PF;                             // issue next prefetch
      tn = tn > (TT - 1) ? (TT - 1) : tn;          // clamped tail (redundant, harmless)
      pf[j] = p[(size_t)tn * stride];

      const float a1 = alpha;
      float a2 = __shfl_up(alpha, 1);
      float a3 = __shfl_up(alpha, 2);
      if (lane < 1) a2 = NEGV;
      a3 = (lane >= 2 && skip) ? a3 : NEGV;
      const float m = fmaxf(fmaxf(a1, a2), a3);
      // all-NEG case: a-m = 0 -> exp = 1, matches reference exactly
      const float ssum = __expf(a1 - m) + __expf(a2 - m) + __expf(a3 - m);
      alpha = m + __logf(ssum) + cur;
    }
  }

  // log-likelihood = logaddexp(alpha[2*len-1], alpha[2*len])
  const float aA = __shfl(alpha, 2 * len - 1);
  const float aB = __shfl(alpha, 2 * len);
  if (lane == 0) {
    const float mm = fmaxf(aA, aB);
    const float ll = mm + __logf(__expf(aA - mm) + __expf(aB - mm));
    float nll = -ll;
    if (nll > 0.5e30f) nll = 0.0f;                 // zero_infinity
    const int dl = len > 1 ? len : 1;
    loss[b] = nll / (float)dl;                     // per-sample mean divisor
  }
}

__global__ __launch_bounds__(256) void ctc_reduce_kernel(
    const float* __restrict__ loss, float* __restrict__ out) {
  float s = 0.f;
  for (int i = threadIdx.x; i < BB; i += 256) s += loss[i];
#pragma unroll
  for (int off = 32; off; off >>= 1) s += __shfl_down(s, off);
  __shared__ float sm[4];
  if ((threadIdx.x & 63) == 0) sm[threadIdx.x >> 6] = s;
  __syncthreads();
  if (threadIdx.x == 0) out[0] = (sm[0] + sm[1] + sm[2] + sm[3]) / (float)BB;
}

extern "C" void kernel_launch(void* const* d_in, const int* in_sizes, int n_in,
                              void* d_out, int out_size, void* d_ws, size_t ws_size,
                              hipStream_t stream) {
  const float* logp  = (const float*)d_in[0];
  const int* targets = (const int*)d_in[1];
  const int* tlen    = (const int*)d_in[2];
  float* out  = (float*)d_out;
  float* loss = (float*)d_ws;   // B floats of per-sample loss
  hipLaunchKernelGGL(ctc_alpha_kernel, dim3(BB / 4), dim3(256), 0, stream,
                     logp, targets, tlen, loss);
  hipLaunchKernelGGL(ctc_reduce_kernel, dim3(1), dim3(256), 0, stream, loss, out);
}

// Round 2
// 55.558 us; speedup vs baseline: 1.4829x; 1.4829x over previous
//
#include <hip/hip_runtime.h>

// CTC loss forward (T=512, B=1024, C=63, S=25, L=51).
// One wave64 per batch element: lane s owns extended state s.
// Cross-lane alpha[s-1], alpha[s-2] via DPP wave_shr1 (no LDS/bpermute).
// Depth-21 register prefetch ring with pointer-increment addressing.

#define TT 512
#define BB 1024
#define CC 63
#define SS 25
#define D  21             // ring depth; main loop = 24 blocks x 21 steps (t=1..504), tail 7
#define NEGV (-1e30f)

__device__ __forceinline__ float wave_shr1(float x, float fill) {
  // whole-wave shift right by one lane: lane s gets x[s-1]; lane 0 gets `fill`
  return __int_as_float(__builtin_amdgcn_update_dpp(
      __float_as_int(fill), __float_as_int(x), 0x138 /*WAVE_SHR1*/, 0xF, 0xF, false));
}

__global__ __launch_bounds__(256) void ctc_alpha_kernel(
    const float* __restrict__ logp,
    const int* __restrict__ targets,
    const int* __restrict__ tlen,
    float* __restrict__ loss) {
  const int lane = threadIdx.x & 63;
  const int b = (blockIdx.x << 2) + (threadIdx.x >> 6);  // 4 waves/block
  const int* tg = targets + b * SS;
  const int len = tlen[b];

  // ext[s]: even s -> blank(0); odd s -> targets[b,(s-1)/2]
  int e = 0;
  bool skip = false;
  if (lane & 1) {
    const int i = lane >> 1;
    if (i < SS) {
      e = tg[i];
      skip = (e != 0) && (i == 0 || e != tg[i - 1]);
    }
  }

  const size_t stride = (size_t)BB * CC;          // floats per timestep
  const float* p = logp + (size_t)b * CC + e;     // this lane's class column

  float alpha = (lane <= 1) ? p[0] : NEGV;        // t=0 init

  // fill prefetch ring with t = 1..D; nx ends at t = D+1
  float pf[D];
  const float* nx = p + stride;
#pragma unroll
  for (int j = 0; j < D; ++j) { pf[j] = nx[0]; nx += stride; }

#define CTC_STEP(CUR)                                              \
  {                                                                \
    const float a1 = alpha;                                        \
    const float a2 = wave_shr1(a1, NEGV);                          \
    float a3 = wave_shr1(a2, NEGV);                                \
    a3 = skip ? a3 : NEGV;                                         \
    const float m = fmaxf(fmaxf(a1, a2), a3);                      \
    const float sm = __expf(a1 - m) + __expf(a2 - m) + __expf(a3 - m); \
    alpha = m + __logf(sm) + (CUR);                                \
  }

  // main loop: t = 1..504, invariant nx = &lp(t + D)
  int t = 1;
  for (int blk = 0; blk < (TT - 1 - 7) / D; ++blk) {
#pragma unroll
    for (int j = 0; j < D; ++j) {
      const float cur = pf[j];
      if (t + D < TT) pf[j] = nx[0];   // uniform guard; false only for t=491..504
      nx += stride;
      CTC_STEP(cur)
      ++t;
    }
  }
  // tail: t = 505..511 live in pf[0..6]
#pragma unroll
  for (int j = 0; j < 7; ++j) { CTC_STEP(pf[j]) }

  // log-likelihood = logaddexp(alpha[2*len-1], alpha[2*len])
  const float aA = __shfl(alpha, 2 * len - 1);
  const float aB = __shfl(alpha, 2 * len);
  if (lane == 0) {
    const float mm = fmaxf(aA, aB);
    const float ll = mm + __logf(__expf(aA - mm) + __expf(aB - mm));
    float nll = -ll;
    if (nll > 0.5e30f) nll = 0.0f;                 // zero_infinity
    const int dl = len > 1 ? len : 1;
    loss[b] = nll / (float)dl;
  }
}

__global__ __launch_bounds__(256) void ctc_reduce_kernel(
    const float* __restrict__ loss, float* __restrict__ out) {
  float s = 0.f;
  for (int i = threadIdx.x; i < BB; i += 256) s += loss[i];
#pragma unroll
  for (int off = 32; off; off >>= 1) s += __shfl_down(s, off);
  __shared__ float sm[4];
  if ((threadIdx.x & 63) == 0) sm[threadIdx.x >> 6] = s;
  __syncthreads();
  if (threadIdx.x == 0) out[0] = (sm[0] + sm[1] + sm[2] + sm[3]) / (float)BB;
}

extern "C" void kernel_launch(void* const* d_in, const int* in_sizes, int n_in,
                              void* d_out, int out_size, void* d_ws, size_t ws_size,
                              hipStream_t stream) {
  const float* logp  = (const float*)d_in[0];
  const int* targets = (const int*)d_in[1];
  const int* tlen    = (const int*)d_in[2];
  float* out  = (float*)d_out;
  float* loss = (float*)d_ws;   // B floats of per-sample loss
  hipLaunchKernelGGL(ctc_alpha_kernel, dim3(BB / 4), dim3(256), 0, stream,
                     logp, targets, tlen, loss);
  hipLaunchKernelGGL(ctc_reduce_kernel, dim3(1), dim3(256), 0, stream, loss, out);
}

// Round 3
// 33.663 us; speedup vs baseline: 2.4475x; 1.6504x over previous
//
#include <hip/hip_runtime.h>

// CTC loss forward (T=512, B=1024, C=63, S=25, L=51).
// One wave64 per batch element; lane s owns extended state s.
// Linear-domain recurrence with per-lane power-of-2 frames:
//   invariant: true alpha[s] = log(A[s]) + M2[s]*ln2
//   step:      A' = P * (A + F1*A[s-1] + F2sk*A[s-2]),  P = exp(lp_t[ext_s])
//   F1,F2 are exact powers of two (frame conversion), refreshed every 16 steps.
// No transcendentals on the critical chain (1 off-chain exp/step on prefetched data).

#define TT 512
#define BB 1024
#define CC 63
#define SS 25
#define D  32              // prefetch ring depth (t+32 ahead)
#define LN2F 0.69314718055994531f

__device__ __forceinline__ float shr1f(float x, float fill) {
  // lane s gets x[s-1]; lane 0 gets fill (wave_shr1, bound_ctrl=false keeps `old`)
  return __int_as_float(__builtin_amdgcn_update_dpp(
      __float_as_int(fill), __float_as_int(x), 0x138, 0xF, 0xF, false));
}
__device__ __forceinline__ int shr1i(int x, int fill) {
  return __builtin_amdgcn_update_dpp(fill, x, 0x138, 0xF, 0xF, false);
}

__global__ __launch_bounds__(256) void ctc_alpha_kernel(
    const float* __restrict__ logp,
    const int* __restrict__ targets,
    const int* __restrict__ tlen,
    float* __restrict__ loss) {
  const int lane = threadIdx.x & 63;
  const int b = (blockIdx.x << 2) + (threadIdx.x >> 6);  // 4 waves/block
  const int* tg = targets + b * SS;
  const int len = tlen[b];

  // ext[s]: even s -> blank(0); odd s -> targets[b,(s-1)/2]; skip = (ext!=0 && ext!=prev2)
  int e = 0;
  float skf = 0.0f;
  if (lane & 1) {
    const int i = lane >> 1;
    if (i < SS) {
      e = tg[i];
      skf = (e != 0 && (i == 0 || e != tg[i - 1])) ? 1.0f : 0.0f;
    }
  }

  const unsigned SB = (unsigned)(BB * CC) * 4u;       // bytes per timestep
  unsigned off = (unsigned)(b * CC + e) * 4u;         // byte offset of lane's class, t=0
  const char* base = (const char*)logp;
#define LDF(O) (*(const float*)(base + (O)))

  // t=0 init: states 0 and 1 reachable
  float A = (lane <= 1) ? __expf(LDF(off)) : 0.0f;
  int M2 = 0;
  float F1 = 1.0f, F2s = skf;

  // ring holds RAW lp for t = (filled)..; exp done at consume (off critical chain)
  float pf[D];
  unsigned offp = off + SB;
#pragma unroll
  for (int j = 0; j < D; ++j) { pf[j] = LDF(offp); offp += SB; }
  // invariant: offp points at t = D+1 relative rows already consumed

#define RENORM() {                                              \
    int e2 = (int)(__float_as_uint(A) >> 23) - 127;             \
    A = ldexpf(A, -e2);              /* exact */                \
    int m2n = M2 + e2;                                          \
    int m2a = shr1i(m2n, 0);                                    \
    M2 = (A == 0.0f) ? m2a : m2n;    /* dead lanes adopt s-1 frame */ \
    int s1 = shr1i(M2, 0);                                      \
    int s2 = shr1i(s1, 0);                                      \
    int d1 = s1 - M2, d2 = s2 - M2;                             \
    d1 = d1 < -126 ? -126 : (d1 > 126 ? 126 : d1);              \
    d2 = d2 < -126 ? -126 : (d2 > 126 ? 126 : d2);              \
    F1 = ldexpf(1.0f, d1);           /* exact pow2 */           \
    F2s = skf * ldexpf(1.0f, d2);                               \
  }

#define STEP(J, PF) {                                           \
    const float P = __expf(pf[(J)]);                            \
    const float a2 = shr1f(A, 0.0f);                            \
    const float a3 = shr1f(a2, 0.0f);                           \
    A = P * fmaf(F2s, a3, fmaf(F1, a2, A));                     \
    if (PF) { pf[(J)] = LDF(offp); offp += SB; }                \
    if (((J) & 15) == 15) RENORM()                              \
  }

  // t = 1..448 : 14 blocks of 32, unguarded prefetch (t+32 <= 480)
  for (int blk = 0; blk < 14; ++blk) {
#pragma unroll
    for (int j = 0; j < D; ++j) STEP(j, true)
  }
  // t = 449..480 : prefetch t+32 = 481..511, skip j=31 (would read t=512)
#pragma unroll
  for (int j = 0; j < D; ++j) STEP(j, j < 31)
  // t = 481..511 : consume ring slots 0..30, no prefetch (renorm hits t=496 at j=15)
#pragma unroll
  for (int j = 0; j < 31; ++j) STEP(j, false)

  // finish: true alpha = M2*ln2 + log(A); ll = logaddexp(alpha[2len-1], alpha[2len])
  const int ia = 2 * len - 1, ib = 2 * len;
  const float aA = __shfl(A, ia), aB = __shfl(A, ib);
  const int mA = __shfl(M2, ia), mB = __shfl(M2, ib);
  if (lane == 0) {
    const float la = (float)mA * LN2F + logf(aA);
    const float lb = (float)mB * LN2F + logf(aB);
    const float m = fmaxf(la, lb);
    const float ll = m + logf(expf(la - m) + expf(lb - m));
    float nll = -ll;
    if (!(nll <= 0.5e30f)) nll = 0.0f;           // zero_infinity (also catches NaN/inf)
    const int dl = len > 1 ? len : 1;
    loss[b] = nll / (float)dl;
  }
}

__global__ __launch_bounds__(256) void ctc_reduce_kernel(
    const float* __restrict__ loss, float* __restrict__ out) {
  float s = 0.f;
  for (int i = threadIdx.x; i < BB; i += 256) s += loss[i];
#pragma unroll
  for (int off = 32; off; off >>= 1) s += __shfl_down(s, off);
  __shared__ float sm[4];
  if ((threadIdx.x & 63) == 0) sm[threadIdx.x >> 6] = s;
  __syncthreads();
  if (threadIdx.x == 0) out[0] = (sm[0] + sm[1] + sm[2] + sm[3]) / (float)BB;
}

extern "C" void kernel_launch(void* const* d_in, const int* in_sizes, int n_in,
                              void* d_out, int out_size, void* d_ws, size_t ws_size,
                              hipStream_t stream) {
  const float* logp  = (const float*)d_in[0];
  const int* targets = (const int*)d_in[1];
  const int* tlen    = (const int*)d_in[2];
  float* out  = (float*)d_out;
  float* loss = (float*)d_ws;   // B floats of per-sample loss
  hipLaunchKernelGGL(ctc_alpha_kernel, dim3(BB / 4), dim3(256), 0, stream,
                     logp, targets, tlen, loss);
  hipLaunchKernelGGL(ctc_reduce_kernel, dim3(1), dim3(256), 0, stream, loss, out);
}

// Round 4
// 32.923 us; speedup vs baseline: 2.5024x; 1.0225x over previous
//
#include <hip/hip_runtime.h>

// CTC loss forward (T=512, B=1024, C=63, S=25, L=51).
// Forward/backward midpoint split: per batch element, wave A computes
// alpha_0..alpha_255 (shift-right recurrence), wave B computes
// beta_511..beta_255 (transposed, shift-left recurrence); combine
// ll = logsum_s(alpha_255[s] + beta_255[s]) via LDS. 2048 waves = 2/SIMD.
// Linear domain with per-lane power-of-2 frames; no trans ops on the chain.

#define TT 512
#define BB 1024
#define CC 63
#define SS 25
#define D  32
#define NEGV (-1e30f)
#define LN2F 0.69314718055994531f

__device__ __forceinline__ float shr1f(float x, float fill) {  // lane s <- x[s-1]
  return __int_as_float(__builtin_amdgcn_update_dpp(
      __float_as_int(fill), __float_as_int(x), 0x138, 0xF, 0xF, false));
}
__device__ __forceinline__ int shr1i(int x, int fill) {
  return __builtin_amdgcn_update_dpp(fill, x, 0x138, 0xF, 0xF, false);
}
__device__ __forceinline__ float shl1f(float x, float fill) {  // lane s <- x[s+1]
  return __int_as_float(__builtin_amdgcn_update_dpp(
      __float_as_int(fill), __float_as_int(x), 0x130, 0xF, 0xF, false));
}
__device__ __forceinline__ int shl1i(int x, int fill) {
  return __builtin_amdgcn_update_dpp(fill, x, 0x130, 0xF, 0xF, false);
}
__device__ __forceinline__ int iclamp126(int d) {
  return d < -126 ? -126 : (d > 126 ? 126 : d);
}

__global__ __launch_bounds__(256) void ctc_fb_kernel(
    const float* __restrict__ logp,
    const int* __restrict__ targets,
    const int* __restrict__ tlen,
    float* __restrict__ loss) {
  const int lane = threadIdx.x & 63;
  const int wid = threadIdx.x >> 6;   // 0..3
  const int pairIdx = wid >> 1;       // which batch element of this block
  const int bwd = wid & 1;
  const int b = (blockIdx.x << 1) + pairIdx;
  const int* tg = targets + b * SS;
  const int len = tlen[b];

  // ext[s]: even s -> blank(0); odd s -> tg[(s-1)/2]
  int e = 0;
  float skf = 0.0f;   // fwd: inflow s-2 -> s allowed
  float skf2 = 0.0f;  // bwd: inflow s+2 -> s allowed (= skip evaluated at s+2)
  if (lane & 1) {
    const int i = lane >> 1;
    if (i < SS) {
      e = tg[i];                                   // >= 1 by construction
      skf = (i == 0 || e != tg[i - 1]) ? 1.0f : 0.0f;
      if (i + 1 < SS) skf2 = (tg[i + 1] != tg[i]) ? 1.0f : 0.0f;
    }
  }

  const unsigned SB = (unsigned)(BB * CC) * 4u;    // bytes per timestep
  const char* base = (const char*)logp;
  const unsigned off0 = (unsigned)(b * CC + e) * 4u;
#define LDF(O) (*(const float*)(base + (O)))

  __shared__ float la_s[2][64];

  float A, F1, F2m;   // F2m carries the skip mask
  int M2 = 0;
  float pf[D];
  unsigned offp;

  if (!bwd) {
    // ---------- forward: alpha at t=0 init, steps t=1..255 ----------
    A = (lane <= 1) ? __expf(LDF(off0)) : 0.0f;
    F1 = 1.0f; F2m = skf;
    offp = off0 + SB;
#pragma unroll
    for (int j = 0; j < D; ++j) { pf[j] = LDF(offp); offp += SB; }

#define RENF() {                                               \
    int e2 = (int)(__float_as_uint(A) >> 23) - 127;            \
    A = ldexpf(A, -e2);                                        \
    int m2n = M2 + e2;                                         \
    int m2a = shr1i(m2n, 0);                                   \
    M2 = (A == 0.0f) ? m2a : m2n;                              \
    int s1 = shr1i(M2, 0), s2 = shr1i(s1, 0);                  \
    F1 = ldexpf(1.0f, iclamp126(s1 - M2));                     \
    F2m = skf * ldexpf(1.0f, iclamp126(s2 - M2));              \
  }
#define STEPF(J, PFLAG) {                                      \
    const float P = __expf(pf[(J)]);                           \
    const float c1 = P * F1, c2 = P * F2m;                     \
    const float a2 = shr1f(A, 0.0f);                           \
    const float pa = P * A;                                    \
    const float a3 = shr1f(a2, 0.0f);                          \
    A = fmaf(c2, a3, fmaf(c1, a2, pa));                        \
    if (PFLAG) { pf[(J)] = LDF(offp); offp += SB; }            \
    if (((J) & 15) == 15) RENF()                               \
  }

    for (int blk = 0; blk < 6; ++blk) {     // t = 1..192
#pragma unroll
      for (int j = 0; j < D; ++j) STEPF(j, true)
    }
#pragma unroll
    for (int j = 0; j < D; ++j) STEPF(j, j < 31)   // t = 193..224
#pragma unroll
    for (int j = 0; j < 31; ++j) STEPF(j, false)   // t = 225..255

    la_s[pairIdx][lane] = fmaxf((float)M2 * LN2F + logf(A), NEGV);
  } else {
    // ---------- backward: beta_511 init, steps consume p_511..p_256 ----------
    A = (lane == 2 * len - 1 || lane == 2 * len) ? 1.0f : 0.0f;
    F1 = 1.0f; F2m = skf2;
    offp = 511u * SB + off0;
#pragma unroll
    for (int j = 0; j < D; ++j) { pf[j] = LDF(offp); offp -= SB; }  // t=511..480

#define RENB() {                                               \
    int e2 = (int)(__float_as_uint(A) >> 23) - 127;            \
    A = ldexpf(A, -e2);                                        \
    int m2n = M2 + e2;                                         \
    int m2a = shl1i(m2n, 0);                                   \
    M2 = (A == 0.0f) ? m2a : m2n;                              \
    int s1 = shl1i(M2, 0), s2 = shl1i(s1, 0);                  \
    F1 = ldexpf(1.0f, iclamp126(s1 - M2));                     \
    F2m = skf2 * ldexpf(1.0f, iclamp126(s2 - M2));             \
  }
#define STEPB(J, PFLAG) {                                      \
    const float P = __expf(pf[(J)]);                           \
    const float P1 = shl1f(P, 0.0f);                           \
    const float P2 = shl1f(P1, 0.0f);                          \
    const float c1 = F1 * P1, c2 = F2m * P2;                   \
    const float a1 = shl1f(A, 0.0f);                           \
    const float pa = P * A;                                    \
    const float a2 = shl1f(a1, 0.0f);                          \
    A = fmaf(c2, a2, fmaf(c1, a1, pa));                        \
    if (PFLAG) { pf[(J)] = LDF(offp); offp -= SB; }            \
    if (((J) & 15) == 15) RENB()                               \
  }

    for (int blk = 0; blk < 7; ++blk) {     // consume t = 511..288, prefetch t-32
#pragma unroll
      for (int j = 0; j < D; ++j) STEPB(j, true)
    }
#pragma unroll
    for (int j = 0; j < D; ++j) STEPB(j, false)    // t = 287..256
  }

  __syncthreads();

  if (bwd) {
    const float lb = fmaxf((float)M2 * LN2F + logf(A), NEGV);
    float v = (lane <= 50) ? la_s[pairIdx][lane] + lb : -2e30f;
    float m = v;
#pragma unroll
    for (int o = 32; o; o >>= 1) m = fmaxf(m, __shfl_xor(m, o));
    float s = __expf(v - m);
#pragma unroll
    for (int o = 32; o; o >>= 1) s += __shfl_xor(s, o);
    if (lane == 0) {
      const float ll = m + logf(s);
      float nll = -ll;
      if (!(nll <= 0.5e30f)) nll = 0.0f;   // zero_infinity (also NaN)
      const int dl = len > 1 ? len : 1;
      loss[b] = nll / (float)dl;
    }
  }
}

__global__ __launch_bounds__(256) void ctc_reduce_kernel(
    const float* __restrict__ loss, float* __restrict__ out) {
  float s = 0.f;
  for (int i = threadIdx.x; i < BB; i += 256) s += loss[i];
#pragma unroll
  for (int off = 32; off; off >>= 1) s += __shfl_down(s, off);
  __shared__ float sm[4];
  if ((threadIdx.x & 63) == 0) sm[threadIdx.x >> 6] = s;
  __syncthreads();
  if (threadIdx.x == 0) out[0] = (sm[0] + sm[1] + sm[2] + sm[3]) / (float)BB;
}

extern "C" void kernel_launch(void* const* d_in, const int* in_sizes, int n_in,
                              void* d_out, int out_size, void* d_ws, size_t ws_size,
                              hipStream_t stream) {
  const float* logp  = (const float*)d_in[0];
  const int* targets = (const int*)d_in[1];
  const int* tlen    = (const int*)d_in[2];
  float* out  = (float*)d_out;
  float* loss = (float*)d_ws;   // B floats of per-sample loss
  hipLaunchKernelGGL(ctc_fb_kernel, dim3(BB / 2), dim3(256), 0, stream,
                     logp, targets, tlen, loss);
  hipLaunchKernelGGL(ctc_reduce_kernel, dim3(1), dim3(256), 0, stream, loss, out);
}